// Round 2
// baseline (418.430 us; speedup 1.0000x reference)
//
#include <hip/hip_runtime.h>
#include <hip/hip_bf16.h>
#include <stdint.h>

#define BB 4
#define NN 16384
#define CC 128
#define MM 2048
#define KNN 16
#define QCAP 1008

typedef unsigned int u32;
typedef unsigned long long u64;

// ---- workspace layout (bytes) ----
#define OFF_FEATT   0ull                    // B*N*C f32   = 33554432
#define OFF_PTS4    33554432ull             // B*N float4  =  4194304
#define OFF_WT      37748736ull             // C*C f32     =    65536
#define OFF_KEYS    37814272ull             // B*N u64     =   524288
#define OFF_VEC     38338560ull             // B*C u32     =     2048
#define OFF_IDX     38340608ull             // B*M u32     =    32768
#define OFF_VAL     38373376ull             // B*M f32     =    32768
#define OFF_TMPK    38406144ull             // B*2*2048 u64=   131072

// numpy-exact f32 distance: ((pw + nw) - 2*(x*nx + y*ny + z*nz)), no FMA
__device__ __forceinline__ float np_dist(float4 p, float4 nd) {
#pragma clang fp contract(off)
    float dot = ((p.x * nd.x) + (p.y * nd.y)) + (p.z * nd.z);
    float d = (p.w + nd.w) - 2.0f * dot;
    return d;
}

__device__ __forceinline__ u32 mono_bits(float d) {
    u32 u = __float_as_uint(d);
    u ^= ((u32)(((int)u) >> 31)) | 0x80000000u;
    return u;
}

// pts4[b][n] = {x,y,z,|p|^2} with numpy-exact |p|^2 = (x*x + y*y) + z*z
__global__ void k_pts(const float* __restrict__ coords, float4* __restrict__ pts4) {
    int i = blockIdx.x * 256 + threadIdx.x;       // < B*N
    int b = i >> 14, n = i & (NN - 1);
    const float* cb = coords + (size_t)b * 3 * NN;
    float x = cb[n], y = cb[NN + n], z = cb[2 * NN + n];
    float w;
    {
#pragma clang fp contract(off)
        w = ((x * x) + (y * y)) + (z * z);
    }
    pts4[i] = make_float4(x, y, z, w);
}

// WT[c][o] = W[o][c]
__global__ void k_wt(const float* __restrict__ W, float* __restrict__ WT) {
    int i = blockIdx.x * 256 + threadIdx.x;       // < C*C
    int o = i >> 7, c = i & 127;
    WT[c * CC + o] = W[i];
}

// feat_t[b][n][c] = feats[b][c][n]
__global__ void k_transpose(const float* __restrict__ feats, float* __restrict__ feat_t) {
    __shared__ float t[64][65];
    int bx = blockIdx.x;
    int b = bx >> 9; int rem = bx & 511; int nb = rem >> 1; int cb2 = rem & 1;
    int n0 = nb * 64, c0 = cb2 * 64;
    int l = threadIdx.x & 63, r0 = threadIdx.x >> 6;
    const float* fb = feats + (size_t)b * CC * NN;
#pragma unroll
    for (int p = 0; p < 16; ++p) {
        int r = r0 + p * 4;
        t[r][l] = fb[(size_t)(c0 + r) * NN + n0 + l];
    }
    __syncthreads();
    float* ob = feat_t + (size_t)b * NN * CC;
#pragma unroll
    for (int p = 0; p < 16; ++p) {
        int r = r0 + p * 4;
        ob[(size_t)(n0 + r) * CC + c0 + l] = t[l][r];
    }
}

// vector[b][o] = max_n relu(sum_c W[o][c] * feats[b][c][n] + bias[o])
__global__ __launch_bounds__(256) void k_vector(const float* __restrict__ feats,
        const float* __restrict__ WT, const float* __restrict__ bias, u32* __restrict__ vecU) {
    __shared__ float zl[CC][64];
    int bx = blockIdx.x;                 // B * (N/64)
    int b = bx >> 8; int n0 = (bx & 255) * 64;
    int l = threadIdx.x & 63;
    const float* fb = feats + (size_t)b * CC * NN + n0;
    for (int c = (threadIdx.x >> 6); c < CC; c += 4)
        zl[c][l] = fb[(size_t)c * NN + l];
    __syncthreads();
    int w = __builtin_amdgcn_readfirstlane(threadIdx.x >> 6);
    int o0 = w * 32;
    float acc[32];
#pragma unroll
    for (int oi = 0; oi < 32; ++oi) acc[oi] = bias[o0 + oi];
    for (int c = 0; c < CC; ++c) {
        float zc = zl[c][l];
        const float4* wt4 = (const float4*)(WT + c * CC + o0);
#pragma unroll
        for (int q = 0; q < 8; ++q) {
            float4 wv = wt4[q];
            acc[q * 4 + 0] = fmaf(wv.x, zc, acc[q * 4 + 0]);
            acc[q * 4 + 1] = fmaf(wv.y, zc, acc[q * 4 + 1]);
            acc[q * 4 + 2] = fmaf(wv.z, zc, acc[q * 4 + 2]);
            acc[q * 4 + 3] = fmaf(wv.w, zc, acc[q * 4 + 3]);
        }
    }
#pragma unroll
    for (int oi = 0; oi < 32; ++oi) {
        float rv = acc[oi] > 0.0f ? acc[oi] : 0.0f;   // relu, +0.0 guaranteed
#pragma unroll
        for (int s = 32; s; s >>= 1) rv = fmaxf(rv, __shfl_xor(rv, s));
        if (l == 0) atomicMax(vecU + b * CC + o0 + oi, __float_as_uint(rv));
    }
}

// keys[b][n] = (mono(sigmoid(sum_c feats*vector)) << 32) | (~n)
__global__ void k_scores(const float* __restrict__ feats, const float* __restrict__ vecF,
                         u64* __restrict__ keys) {
    int i = blockIdx.x * 256 + threadIdx.x;    // < B*N
    int b = i >> 14, n = i & (NN - 1);
    const float* fb = feats + (size_t)b * CC * NN + n;
    const float* vb = vecF + b * CC;
    float wsum = 0.f;
#pragma unroll 8
    for (int c = 0; c < CC; ++c) wsum = fmaf(fb[(size_t)c * NN], vb[c], wsum);
    float s = 1.0f / (1.0f + expf(-wsum));     // scores >= 0 -> bits monotonic
    u32 mono = __float_as_uint(s);
    keys[i] = ((u64)mono << 32) | (u64)(0xFFFFFFFFu - (u32)n);
}

// sort one 8192 half descending, emit its top-2048
__global__ __launch_bounds__(1024) void k_sort8k(const u64* __restrict__ keys, u64* __restrict__ tmpK) {
    __shared__ u64 sk[8192];
    int b = blockIdx.x >> 1, h = blockIdx.x & 1;
    int tid = threadIdx.x;
    const u64* src = keys + (size_t)b * NN + h * 8192;
#pragma unroll
    for (int j = 0; j < 8; ++j) sk[tid + 1024 * j] = src[tid + 1024 * j];
    for (int size = 2; size <= 8192; size <<= 1) {
        for (int stride = size >> 1; stride > 0; stride >>= 1) {
            __syncthreads();
            for (int t = tid; t < 4096; t += 1024) {
                int i = (t << 1) - (t & (stride - 1));
                int j = i + stride;
                u64 a = sk[i], c = sk[j];
                bool up = ((i & size) == 0);
                if ((a < c) == up) { sk[i] = c; sk[j] = a; }
            }
        }
    }
    __syncthreads();
    u64* dst = tmpK + (size_t)(b * 2 + h) * 2048;
    for (int t = tid; t < 2048; t += 1024) dst[t] = sk[t];
}

// merge two descending 2048 lists -> top 2048 -> idx/val
__global__ __launch_bounds__(1024) void k_merge(const u64* __restrict__ tmpK,
        u32* __restrict__ idxA, float* __restrict__ valA) {
    __shared__ u64 mk[4096];
    int b = blockIdx.x, tid = threadIdx.x;
    const u64* s0 = tmpK + (size_t)(b * 2) * 2048;
    const u64* s1 = s0 + 2048;
    for (int t = tid; t < 2048; t += 1024) { mk[t] = s0[t]; mk[2048 + t] = s1[2047 - t]; }
    for (int stride = 2048; stride > 0; stride >>= 1) {
        __syncthreads();
        for (int t = tid; t < 2048; t += 1024) {
            int i = (t << 1) - (t & (stride - 1));
            int j = i + stride;
            u64 a = mk[i], c = mk[j];
            if (a < c) { mk[i] = c; mk[j] = a; }
        }
    }
    __syncthreads();
    for (int t = tid; t < 2048; t += 1024) {
        u64 k = mk[t];
        idxA[b * MM + t] = 0xFFFFFFFFu - (u32)(k & 0xFFFFFFFFull);
        valA[b * MM + t] = __uint_as_float((u32)(k >> 32));
    }
}

// outputs 0,1 and first half of output 2
__global__ void k_gather(const float4* __restrict__ pts4, const float* __restrict__ feat_t,
        const u32* __restrict__ idxA, const float* __restrict__ valA, float* __restrict__ out) {
    int g = blockIdx.x * 256 + threadIdx.x;    // < B*M
    int b = g >> 11, i = g & (MM - 1);
    u32 n = idxA[g];
    float v = valA[g];
    float4 p = pts4[(b << 14) + (int)n];
    float* o0 = out + (size_t)b * 3 * MM + i;
    o0[0] = p.x; o0[MM] = p.y; o0[2 * MM] = p.z;
    float* o1 = o0 + 24576;
    o1[0] = p.x * v; o1[MM] = p.y * v; o1[2 * MM] = p.z * v;
    const float4* ft = (const float4*)(feat_t + ((size_t)(b << 14) + n) * CC);
    float* o2 = out + 49152 + ((size_t)b * 256) * MM + i;
#pragma unroll 8
    for (int q = 0; q < 32; ++q) {
        float4 f = ft[q];
        o2[(size_t)(4 * q + 0) * MM] = f.x * v;
        o2[(size_t)(4 * q + 1) * MM] = f.y * v;
        o2[(size_t)(4 * q + 2) * MM] = f.z * v;
        o2[(size_t)(4 * q + 3) * MM] = f.w * v;
    }
}

// kNN(k=16) + channel-max aggregation -> second half of output 2
__global__ __launch_bounds__(256) void k_knn(const float4* __restrict__ pts4,
        const float* __restrict__ feat_t, const u32* __restrict__ idxA, float* __restrict__ out) {
    __shared__ float4 ptsS[2048];
    __shared__ u64 qS[4][QCAP];
    __shared__ float4 nodeS[4];
    int bx = blockIdx.x;
    int b = bx >> 9, mblk = bx & 511;
    int tid = threadIdx.x, l = tid & 63;
    const float4* pb = pts4 + (b << 14);
    if (tid < 4) nodeS[tid] = pb[idxA[b * MM + mblk * 4 + tid]];
#pragma unroll
    for (int j = 0; j < 8; ++j) ptsS[tid + 256 * j] = pb[tid + 256 * j];
    __syncthreads();
    int w = __builtin_amdgcn_readfirstlane(tid >> 6);
    float4 nd = nodeS[w];
    // pass 1: per-lane min over chunk 0, then 16th-smallest of 64 lane-mins = threshold
    u32 lmin = 0xFFFFFFFFu;
#pragma unroll 4
    for (int j = 0; j < 32; ++j) {
        float4 p = ptsS[l + 64 * j];
        u32 u = mono_bits(np_dist(p, nd));
        lmin = min(lmin, u);
    }
    u32 sv = lmin;
#pragma unroll
    for (int k = 2; k <= 64; k <<= 1) {
#pragma unroll
        for (int j = k >> 1; j > 0; j >>= 1) {
            u32 pv = (u32)__shfl_xor((int)sv, j);
            bool up = ((l & k) == 0);
            bool tmin = (((l & j) == 0) == up);
            u32 mn = min(sv, pv), mx = max(sv, pv);
            sv = tmin ? mn : mx;
        }
    }
    u32 T = (u32)__shfl((int)sv, 15);
    // pass 2: compact survivors (d <= T) into per-wave queue
    int qc = 0;
    for (int ch = 0; ch < 8; ++ch) {
        if (ch > 0) {
            __syncthreads();
#pragma unroll
            for (int j = 0; j < 8; ++j) ptsS[tid + 256 * j] = pb[ch * 2048 + tid + 256 * j];
            __syncthreads();
        }
        for (int j = 0; j < 32; ++j) {
            float4 p = ptsS[l + 64 * j];
            u32 u = mono_bits(np_dist(p, nd));
            bool pred = (u <= T);
            u64 bal = __ballot(pred);
            if (bal) {
                int off = (int)__popcll(bal & ((1ull << l) - 1ull));
                int slot = qc + off;
                if (pred && slot < QCAP) qS[w][slot] = ((u64)u << 32) | (u64)(ch * 2048 + l + 64 * j);
                qc += (int)__popcll(bal);
            }
        }
    }
    __syncthreads();
    // pass 3+4: 16x exact wave-argmin (ties -> smallest n) fused with gather+max
    int qcap = qc < QCAP ? qc : QCAP;
    u64 regk[16];
#pragma unroll
    for (int s = 0; s < 16; ++s) {
        int pos = (s << 6) + l;
        regk[s] = (pos < qcap) ? qS[w][pos] : ~0ull;
    }
    float mx0 = -3.0e38f, mx1 = -3.0e38f;
    int m = mblk * 4 + w;
    for (int it = 0; it < KNN; ++it) {
        u64 mykey = ~0ull;
#pragma unroll
        for (int s = 0; s < 16; ++s) mykey = regk[s] < mykey ? regk[s] : mykey;
        u64 r = mykey;
#pragma unroll
        for (int j = 32; j > 0; j >>= 1) {
            u64 o = __shfl_xor(r, j);
            r = o < r ? o : r;
        }
#pragma unroll
        for (int s = 0; s < 16; ++s) if (regk[s] == r) regk[s] = ~0ull;
        if (r != ~0ull) {
            u32 nj = (u32)(r & 0xFFFFFFFFull);
            const float2 f = *(const float2*)(feat_t + ((size_t)(b << 14) + nj) * CC + (l << 1));
            mx0 = fmaxf(mx0, f.x);
            mx1 = fmaxf(mx1, f.y);
        }
    }
    size_t ob = 49152 + ((size_t)(b * 256 + 128 + 2 * l)) * MM + m;
    out[ob] = mx0;
    out[ob + MM] = mx1;
}

extern "C" void kernel_launch(void* const* d_in, const int* in_sizes, int n_in,
                              void* d_out, int out_size, void* d_ws, size_t ws_size,
                              hipStream_t stream) {
    const float* coords = (const float*)d_in[0];
    const float* feats  = (const float*)d_in[1];
    const float* W      = (const float*)d_in[2];
    const float* bias   = (const float*)d_in[3];
    char* ws = (char*)d_ws;
    float*  feat_t = (float*)(ws + OFF_FEATT);
    float4* pts4   = (float4*)(ws + OFF_PTS4);
    float*  WT     = (float*)(ws + OFF_WT);
    u64*    keys   = (u64*)(ws + OFF_KEYS);
    u32*    vecU   = (u32*)(ws + OFF_VEC);
    u32*    idxA   = (u32*)(ws + OFF_IDX);
    float*  valA   = (float*)(ws + OFF_VAL);
    u64*    tmpK   = (u64*)(ws + OFF_TMPK);
    float*  out    = (float*)d_out;

    hipMemsetAsync(vecU, 0, BB * CC * sizeof(u32), stream);
    k_pts      <<<BB * NN / 256, 256, 0, stream>>>(coords, pts4);
    k_wt       <<<CC * CC / 256, 256, 0, stream>>>(W, WT);
    k_transpose<<<BB * (NN / 64) * (CC / 64), 256, 0, stream>>>(feats, feat_t);
    k_vector   <<<BB * (NN / 64), 256, 0, stream>>>(feats, WT, bias, vecU);
    k_scores   <<<BB * NN / 256, 256, 0, stream>>>(feats, (const float*)vecU, keys);
    k_sort8k   <<<BB * 2, 1024, 0, stream>>>(keys, tmpK);
    k_merge    <<<BB, 1024, 0, stream>>>(tmpK, idxA, valA);
    k_gather   <<<BB * MM / 256, 256, 0, stream>>>(pts4, feat_t, idxA, valA, out);
    k_knn      <<<BB * (MM / 4), 256, 0, stream>>>(pts4, feat_t, idxA, out);
}

// Round 3
// 321.811 us; speedup vs baseline: 1.3002x; 1.3002x over previous
//
#include <hip/hip_runtime.h>
#include <hip/hip_bf16.h>
#include <stdint.h>

#define BB 4
#define NN 16384
#define CC 128
#define MM 2048
#define KNN 16
#define QCAP 736

typedef unsigned int u32;
typedef unsigned long long u64;

// ---- workspace layout (bytes) ----
#define OFF_FEATT   0ull                    // B*N*C f32   = 33554432
#define OFF_PTS4    33554432ull             // B*N float4  =  4194304
#define OFF_WT      37748736ull             // C*C f32     =    65536
#define OFF_KEYS    37814272ull             // B*N u64     =   524288
#define OFF_VEC     38338560ull             // B*C u32     =     2048
#define OFF_IDX     38340608ull             // B*M u32     =    32768
#define OFF_VAL     38373376ull             // B*M f32     =    32768
#define OFF_TMP1    38406144ull             // B*4*2048 u64=   262144
#define OFF_TMP2    38668288ull             // B*2*2048 u64=   131072

// numpy-exact f32 distance: ((pw + nw) - 2*(x*nx + y*ny + z*nz)), no FMA
__device__ __forceinline__ float np_dist(float4 p, float4 nd) {
#pragma clang fp contract(off)
    float dot = ((p.x * nd.x) + (p.y * nd.y)) + (p.z * nd.z);
    float d = (p.w + nd.w) - 2.0f * dot;
    return d;
}

__device__ __forceinline__ u32 mono_bits(float d) {
    u32 u = __float_as_uint(d);
    u ^= ((u32)(((int)u) >> 31)) | 0x80000000u;
    return u;
}

// pts4[b][n] = {x,y,z,|p|^2} with numpy-exact |p|^2 = (x*x + y*y) + z*z
__global__ void k_pts(const float* __restrict__ coords, float4* __restrict__ pts4) {
    int i = blockIdx.x * 256 + threadIdx.x;       // < B*N
    int b = i >> 14, n = i & (NN - 1);
    const float* cb = coords + (size_t)b * 3 * NN;
    float x = cb[n], y = cb[NN + n], z = cb[2 * NN + n];
    float w;
    {
#pragma clang fp contract(off)
        w = ((x * x) + (y * y)) + (z * z);
    }
    pts4[i] = make_float4(x, y, z, w);
}

// WT[c][o] = W[o][c]
__global__ void k_wt(const float* __restrict__ W, float* __restrict__ WT) {
    int i = blockIdx.x * 256 + threadIdx.x;       // < C*C
    int o = i >> 7, c = i & 127;
    WT[c * CC + o] = W[i];
}

// feat_t[b][n][c] = feats[b][c][n]
__global__ void k_transpose(const float* __restrict__ feats, float* __restrict__ feat_t) {
    __shared__ float t[64][65];
    int bx = blockIdx.x;
    int b = bx >> 9; int rem = bx & 511; int nb = rem >> 1; int cb2 = rem & 1;
    int n0 = nb * 64, c0 = cb2 * 64;
    int l = threadIdx.x & 63, r0 = threadIdx.x >> 6;
    const float* fb = feats + (size_t)b * CC * NN;
#pragma unroll
    for (int p = 0; p < 16; ++p) {
        int r = r0 + p * 4;
        t[r][l] = fb[(size_t)(c0 + r) * NN + n0 + l];
    }
    __syncthreads();
    float* ob = feat_t + (size_t)b * NN * CC;
#pragma unroll
    for (int p = 0; p < 16; ++p) {
        int r = r0 + p * 4;
        ob[(size_t)(n0 + r) * CC + c0 + l] = t[l][r];
    }
}

// vector[b][o] = max_n relu(sum_c W[o][c] * feats[b][c][n] + bias[o])
__global__ __launch_bounds__(256) void k_vector(const float* __restrict__ feats,
        const float* __restrict__ WT, const float* __restrict__ bias, u32* __restrict__ vecU) {
    __shared__ float zl[CC][64];
    int bx = blockIdx.x;                 // B * (N/64)
    int b = bx >> 8; int n0 = (bx & 255) * 64;
    int l = threadIdx.x & 63;
    const float* fb = feats + (size_t)b * CC * NN + n0;
    for (int c = (threadIdx.x >> 6); c < CC; c += 4)
        zl[c][l] = fb[(size_t)c * NN + l];
    __syncthreads();
    int w = __builtin_amdgcn_readfirstlane(threadIdx.x >> 6);
    int o0 = w * 32;
    float acc[32];
#pragma unroll
    for (int oi = 0; oi < 32; ++oi) acc[oi] = bias[o0 + oi];
    for (int c = 0; c < CC; ++c) {
        float zc = zl[c][l];
        const float4* wt4 = (const float4*)(WT + c * CC + o0);
#pragma unroll
        for (int q = 0; q < 8; ++q) {
            float4 wv = wt4[q];
            acc[q * 4 + 0] = fmaf(wv.x, zc, acc[q * 4 + 0]);
            acc[q * 4 + 1] = fmaf(wv.y, zc, acc[q * 4 + 1]);
            acc[q * 4 + 2] = fmaf(wv.z, zc, acc[q * 4 + 2]);
            acc[q * 4 + 3] = fmaf(wv.w, zc, acc[q * 4 + 3]);
        }
    }
#pragma unroll
    for (int oi = 0; oi < 32; ++oi) {
        float rv = acc[oi] > 0.0f ? acc[oi] : 0.0f;   // relu, +0.0 guaranteed
#pragma unroll
        for (int s = 32; s; s >>= 1) rv = fmaxf(rv, __shfl_xor(rv, s));
        if (l == 0) atomicMax(vecU + b * CC + o0 + oi, __float_as_uint(rv));
    }
}

// keys[b][n] = (mono(sigmoid(sum_c feats*vector)) << 32) | (~n)
__global__ void k_scores(const float* __restrict__ feats, const float* __restrict__ vecF,
                         u64* __restrict__ keys) {
    int i = blockIdx.x * 256 + threadIdx.x;    // < B*N
    int b = i >> 14, n = i & (NN - 1);
    const float* fb = feats + (size_t)b * CC * NN + n;
    const float* vb = vecF + b * CC;
    float wsum = 0.f;
#pragma unroll 8
    for (int c = 0; c < CC; ++c) wsum = fmaf(fb[(size_t)c * NN], vb[c], wsum);
    float s = 1.0f / (1.0f + expf(-wsum));     // scores >= 0 -> bits monotonic
    u32 mono = __float_as_uint(s);
    keys[i] = ((u64)mono << 32) | (u64)(0xFFFFFFFFu - (u32)n);
}

// sort one 2048-key chunk descending, in place (32 blocks)
__global__ __launch_bounds__(512) void k_sortchunk(u64* __restrict__ keys) {
    __shared__ u64 sk[2048];
    int b = blockIdx.x >> 3, c = blockIdx.x & 7;
    int tid = threadIdx.x;
    u64* src = keys + (size_t)b * NN + c * 2048;
#pragma unroll
    for (int j = 0; j < 4; ++j) sk[tid + 512 * j] = src[tid + 512 * j];
    for (int size = 2; size <= 2048; size <<= 1) {
        for (int stride = size >> 1; stride > 0; stride >>= 1) {
            __syncthreads();
            for (int t = tid; t < 1024; t += 512) {
                int i = (t << 1) - (t & (stride - 1));
                int j = i + stride;
                u64 a = sk[i], cc = sk[j];
                bool up = ((i & size) == 0);
                if ((a < cc) == up) { sk[i] = cc; sk[j] = a; }
            }
        }
    }
    __syncthreads();
#pragma unroll
    for (int j = 0; j < 4; ++j) src[tid + 512 * j] = sk[tid + 512 * j];
}

// merge two descending 2048-lists -> top-2048 (descending)
__global__ __launch_bounds__(512) void k_mergetop(const u64* __restrict__ in,
        u64* __restrict__ outp, int lg /* log2(pairs per batch) */) {
    __shared__ u64 mk[4096];
    int b = blockIdx.x >> lg, pr = blockIdx.x & ((1 << lg) - 1);
    int tid = threadIdx.x;
    const u64* s0 = in + ((size_t)((b << lg) + pr) * 2) * 2048;
    const u64* s1 = s0 + 2048;
    for (int t = tid; t < 2048; t += 512) { mk[t] = s0[t]; mk[2048 + t] = s1[2047 - t]; }
    __syncthreads();
    // half-cleaner: top half of bitonic 4096 = the 2048 largest
    for (int t = tid; t < 2048; t += 512) {
        u64 a = mk[t], c = mk[t + 2048];
        if (a < c) { mk[t] = c; mk[t + 2048] = a; }
    }
    // sort first 2048 (bitonic) descending
    for (int stride = 1024; stride > 0; stride >>= 1) {
        __syncthreads();
        for (int t = tid; t < 1024; t += 512) {
            int i = (t << 1) - (t & (stride - 1));
            int j = i + stride;
            u64 a = mk[i], c = mk[j];
            if (a < c) { mk[i] = c; mk[j] = a; }
        }
    }
    __syncthreads();
    u64* dst = outp + (size_t)((b << lg) + pr) * 2048;
    for (int t = tid; t < 2048; t += 512) dst[t] = mk[t];
}

// final merge -> idxA/valA
__global__ __launch_bounds__(512) void k_mergefinal(const u64* __restrict__ in,
        u32* __restrict__ idxA, float* __restrict__ valA) {
    __shared__ u64 mk[4096];
    int b = blockIdx.x, tid = threadIdx.x;
    const u64* s0 = in + (size_t)(b * 2) * 2048;
    const u64* s1 = s0 + 2048;
    for (int t = tid; t < 2048; t += 512) { mk[t] = s0[t]; mk[2048 + t] = s1[2047 - t]; }
    __syncthreads();
    for (int t = tid; t < 2048; t += 512) {
        u64 a = mk[t], c = mk[t + 2048];
        if (a < c) { mk[t] = c; mk[t + 2048] = a; }
    }
    for (int stride = 1024; stride > 0; stride >>= 1) {
        __syncthreads();
        for (int t = tid; t < 1024; t += 512) {
            int i = (t << 1) - (t & (stride - 1));
            int j = i + stride;
            u64 a = mk[i], c = mk[j];
            if (a < c) { mk[i] = c; mk[j] = a; }
        }
    }
    __syncthreads();
    for (int t = tid; t < 2048; t += 512) {
        u64 k = mk[t];
        idxA[b * MM + t] = 0xFFFFFFFFu - (u32)(k & 0xFFFFFFFFull);
        valA[b * MM + t] = __uint_as_float((u32)(k >> 32));
    }
}

// outputs 0,1 and first half of output 2
__global__ void k_gather(const float4* __restrict__ pts4, const float* __restrict__ feat_t,
        const u32* __restrict__ idxA, const float* __restrict__ valA, float* __restrict__ out) {
    int g = blockIdx.x * 256 + threadIdx.x;    // < B*M
    int b = g >> 11, i = g & (MM - 1);
    u32 n = idxA[g];
    float v = valA[g];
    float4 p = pts4[(b << 14) + (int)n];
    float* o0 = out + (size_t)b * 3 * MM + i;
    o0[0] = p.x; o0[MM] = p.y; o0[2 * MM] = p.z;
    float* o1 = o0 + 24576;
    o1[0] = p.x * v; o1[MM] = p.y * v; o1[2 * MM] = p.z * v;
    const float4* ft = (const float4*)(feat_t + ((size_t)(b << 14) + n) * CC);
    float* o2 = out + 49152 + ((size_t)b * 256) * MM + i;
#pragma unroll 8
    for (int q = 0; q < 32; ++q) {
        float4 f = ft[q];
        o2[(size_t)(4 * q + 0) * MM] = f.x * v;
        o2[(size_t)(4 * q + 1) * MM] = f.y * v;
        o2[(size_t)(4 * q + 2) * MM] = f.z * v;
        o2[(size_t)(4 * q + 3) * MM] = f.w * v;
    }
}

// kNN(k=16) + channel-max aggregation -> second half of output 2
// 4 waves/block, 1 node/wave; 1024-pt LDS chunks; float threshold in sweep
__global__ __launch_bounds__(256) void k_knn(const float4* __restrict__ pts4,
        const float* __restrict__ feat_t, const u32* __restrict__ idxA, float* __restrict__ out) {
    __shared__ float4 ptsS[1024];
    __shared__ u64 qS[4][QCAP];
    __shared__ float4 nodeS[4];
    int bx = blockIdx.x;
    int b = bx >> 9, mblk = bx & 511;
    int tid = threadIdx.x, l = tid & 63;
    const float4* pb = pts4 + (b << 14);
    if (tid < 4) nodeS[tid] = pb[idxA[b * MM + mblk * 4 + tid]];
#pragma unroll
    for (int j = 0; j < 4; ++j) ptsS[tid + 256 * j] = pb[tid + 256 * j];
    __syncthreads();
    int w = __builtin_amdgcn_readfirstlane(tid >> 6);
    float4 nd = nodeS[w];
    // pass 1: lane-min over first 2048 points (2 chunks), then 16th-smallest of 64 lane-mins
    float lmin = 3.0e38f;
#pragma unroll 4
    for (int j = 0; j < 16; ++j) lmin = fminf(lmin, np_dist(ptsS[l + 64 * j], nd));
    __syncthreads();
#pragma unroll
    for (int j = 0; j < 4; ++j) ptsS[tid + 256 * j] = pb[1024 + tid + 256 * j];
    __syncthreads();
#pragma unroll 4
    for (int j = 0; j < 16; ++j) lmin = fminf(lmin, np_dist(ptsS[l + 64 * j], nd));
    float sv = lmin;
#pragma unroll
    for (int k = 2; k <= 64; k <<= 1) {
#pragma unroll
        for (int j = k >> 1; j > 0; j >>= 1) {
            float pv = __shfl_xor(sv, j);
            bool up = ((l & k) == 0);
            bool tmin = (((l & j) == 0) == up);
            float mn = fminf(sv, pv), mx = fmaxf(sv, pv);
            sv = tmin ? mn : mx;
        }
    }
    float T = __shfl(sv, 15);     // >= true 16th-NN distance (16 disjoint-lane points <= T)
    // pass 2: compact survivors (d <= T) into per-wave queue
    int qc = 0;
    for (int ch = 0; ch < 16; ++ch) {
        __syncthreads();
#pragma unroll
        for (int j = 0; j < 4; ++j) ptsS[tid + 256 * j] = pb[ch * 1024 + tid + 256 * j];
        __syncthreads();
        for (int j = 0; j < 16; ++j) {
            float4 p = ptsS[l + 64 * j];
            float d = np_dist(p, nd);
            bool pred = (d <= T);
            u64 bal = __ballot(pred);
            if (bal) {
                int off = (int)__popcll(bal & ((1ull << l) - 1ull));
                int slot = qc + off;
                if (pred && slot < QCAP)
                    qS[w][slot] = ((u64)mono_bits(d) << 32) | (u64)(ch * 1024 + l + 64 * j);
                qc += (int)__popcll(bal);
            }
        }
    }
    __syncthreads();
    // pass 3+4: 16x exact wave-argmin (ties -> smallest n) fused with gather+max
    int qcap = qc < QCAP ? qc : QCAP;
    u64 regk[12];
#pragma unroll
    for (int s = 0; s < 12; ++s) {
        int pos = (s << 6) + l;
        regk[s] = (pos < qcap) ? qS[w][pos] : ~0ull;
    }
    float mx0 = -3.0e38f, mx1 = -3.0e38f;
    int m = mblk * 4 + w;
    for (int it = 0; it < KNN; ++it) {
        u64 mykey = ~0ull;
#pragma unroll
        for (int s = 0; s < 12; ++s) mykey = regk[s] < mykey ? regk[s] : mykey;
        u64 r = mykey;
#pragma unroll
        for (int j = 32; j > 0; j >>= 1) {
            u64 o = __shfl_xor(r, j);
            r = o < r ? o : r;
        }
#pragma unroll
        for (int s = 0; s < 12; ++s) if (regk[s] == r) regk[s] = ~0ull;
        if (r != ~0ull) {
            u32 nj = (u32)(r & 0xFFFFFFFFull);
            const float2 f = *(const float2*)(feat_t + ((size_t)(b << 14) + nj) * CC + (l << 1));
            mx0 = fmaxf(mx0, f.x);
            mx1 = fmaxf(mx1, f.y);
        }
    }
    size_t ob = 49152 + ((size_t)(b * 256 + 128 + 2 * l)) * MM + m;
    out[ob] = mx0;
    out[ob + MM] = mx1;
}

extern "C" void kernel_launch(void* const* d_in, const int* in_sizes, int n_in,
                              void* d_out, int out_size, void* d_ws, size_t ws_size,
                              hipStream_t stream) {
    const float* coords = (const float*)d_in[0];
    const float* feats  = (const float*)d_in[1];
    const float* W      = (const float*)d_in[2];
    const float* bias   = (const float*)d_in[3];
    char* ws = (char*)d_ws;
    float*  feat_t = (float*)(ws + OFF_FEATT);
    float4* pts4   = (float4*)(ws + OFF_PTS4);
    float*  WT     = (float*)(ws + OFF_WT);
    u64*    keys   = (u64*)(ws + OFF_KEYS);
    u32*    vecU   = (u32*)(ws + OFF_VEC);
    u32*    idxA   = (u32*)(ws + OFF_IDX);
    float*  valA   = (float*)(ws + OFF_VAL);
    u64*    tmp1   = (u64*)(ws + OFF_TMP1);
    u64*    tmp2   = (u64*)(ws + OFF_TMP2);
    float*  out    = (float*)d_out;

    hipMemsetAsync(vecU, 0, BB * CC * sizeof(u32), stream);
    k_pts      <<<BB * NN / 256, 256, 0, stream>>>(coords, pts4);
    k_wt       <<<CC * CC / 256, 256, 0, stream>>>(W, WT);
    k_transpose<<<BB * (NN / 64) * (CC / 64), 256, 0, stream>>>(feats, feat_t);
    k_vector   <<<BB * (NN / 64), 256, 0, stream>>>(feats, WT, bias, vecU);
    k_scores   <<<BB * NN / 256, 256, 0, stream>>>(feats, (const float*)vecU, keys);
    k_sortchunk<<<BB * 8, 512, 0, stream>>>(keys);
    k_mergetop <<<BB * 4, 512, 0, stream>>>(keys, tmp1, 2);
    k_mergetop <<<BB * 2, 512, 0, stream>>>(tmp1, tmp2, 1);
    k_mergefinal<<<BB, 512, 0, stream>>>(tmp2, idxA, valA);
    k_gather   <<<BB * MM / 256, 256, 0, stream>>>(pts4, feat_t, idxA, valA, out);
    k_knn      <<<BB * (MM / 4), 256, 0, stream>>>(pts4, feat_t, idxA, out);
}